// Round 1
// baseline (168.380 us; speedup 1.0000x reference)
//
#include <hip/hip_runtime.h>
#include <stdint.h>

// ---------------------------------------------------------------------------
// WeightGenerator_V4, round 4: fuse k2a into k2b.
//   k1a: grouped 3x3 conv -> xr fp32. 128 blocks.
//   k1b: gate(1x1+BN+StarReLU) + dw3/dw5 + mul -> xc bf16; w_lin -> bf16.
//   k2 : FUSED. Per patch: generate Wd chunks (256e x 32c bf16) into LDS
//        from xc (B-frag, M=8 groups) x wlin (A-frag, rows = c) MFMAs,
//        double-buffered, then consume with the barrier-free MFMA loop.
//        Eliminates the 64 MB Wd HBM round-trip (134 MB of traffic) and
//        the entire k2a dispatch. wlin re-reads are L2-resident (256 KB).
//        LDS: Ylds 32 KB + (scratch 32 KB aliased as Wd dbuf 2x16 KB)
//        = 64 KB -> 2 blocks/CU, 512 blocks = 1 round.
// ---------------------------------------------------------------------------

typedef __attribute__((ext_vector_type(8))) short short8;
typedef __attribute__((ext_vector_type(4))) float f32x4;

#define BN_EPS 1e-5f

__device__ __forceinline__ unsigned short f2bf(float f) {
  unsigned u = __float_as_uint(f);
  return (unsigned short)((u + 0x8000u) >> 16);
}
__device__ __forceinline__ unsigned pk2bf(float a, float b) {
  unsigned ua = __float_as_uint(a), ub = __float_as_uint(b);
  return ((ua + 0x8000u) >> 16) | ((ub + 0x8000u) & 0xFFFF0000u);
}

// =====================  k1a: grouped 3x3 conv -> xr  =====================
__global__ __launch_bounds__(256) void k1a_groupconv(
    const float* __restrict__ x, const float* __restrict__ w_cr,
    const float* __restrict__ b_cr, float* __restrict__ xr)
{
  __shared__ float xs[4][256];
  int b = blockIdx.x >> 6, cr = blockIdx.x & 63;
  int t = threadIdx.x;
  {
    int ch = t >> 6, off = (t & 63) * 4;
    float4 v = *(const float4*)(x + b * 65536 + (cr * 4 + ch) * 256 + off);
    *(float4*)&xs[ch][off] = v;
  }
  __syncthreads();
  int h = t >> 4, w = t & 15;
  float a = b_cr[cr];
  #pragma unroll
  for (int ii = 0; ii < 4; ++ii) {
    const float* wp = w_cr + (cr * 4 + ii) * 9;
    #pragma unroll
    for (int ky = 0; ky < 3; ++ky) {
      int gy = h + ky - 1;
      #pragma unroll
      for (int kx = 0; kx < 3; ++kx) {
        int gx = w + kx - 1;
        float v = (gy >= 0 && gy < 16 && gx >= 0 && gx < 16) ? xs[ii][gy * 16 + gx] : 0.f;
        a += wp[ky * 3 + kx] * v;
      }
    }
  }
  xr[(b * 64 + cr) * 256 + t] = a;
}

// =====================  k1b: gate + dw + multiply -> xc  =====================
__global__ __launch_bounds__(256) void k1b_gate_dw(
    const float* __restrict__ x, const float* __restrict__ xr,
    const float* __restrict__ w_dw3, const float* __restrict__ b_dw3,
    const float* __restrict__ w_dw7, const float* __restrict__ b_dw7,
    const float* __restrict__ w_gate, const float* __restrict__ b_gate,
    const float* __restrict__ bn_gamma, const float* __restrict__ bn_beta,
    const float* __restrict__ bn_mean, const float* __restrict__ bn_var,
    const float* __restrict__ sr_scale, const float* __restrict__ sr_bias,
    const float* __restrict__ w_lin, short* __restrict__ wlin_bf, short* __restrict__ xc_bf)
{
  __shared__ float xcen[256];
  __shared__ float gs[128];
  int blk = blockIdx.x;
  int b = blk >> 8, h = (blk >> 4) & 15, w = blk & 15;
  int t = threadIdx.x;

  { int idx = blk * 256 + t; wlin_bf[idx] = (short)f2bf(w_lin[idx]); }

  xcen[t] = x[b * 65536 + t * 256 + h * 16 + w];
  __syncthreads();

  int o = t >> 1, half = t & 1;
  {
    const float* wrow = w_gate + o * 256 + half * 128;
    const float* xcn  = xcen + half * 128;
    float ga = 0.f;
    #pragma unroll 8
    for (int ci = 0; ci < 128; ci += 4) {
      float4 wv = *(const float4*)(wrow + ci);
      float4 xv = *(const float4*)(xcn + ci);
      ga += wv.x * xv.x + wv.y * xv.y + wv.z * xv.z + wv.w * xv.w;
    }
    ga += __shfl_xor(ga, 1);
    float inv = bn_gamma[o] * rsqrtf(bn_var[o] + BN_EPS);
    float gg = (ga + b_gate[o] - bn_mean[o]) * inv + bn_beta[o];
    gg = fmaxf(gg, 0.f);
    gg = sr_scale[0] * gg * gg + sr_bias[0];
    if (half == 0) gs[o] = gg;
  }
  __syncthreads();

  if (t < 128) {
    int oc = t;
    float f0;
    if (oc < 64) {
      f0 = b_dw3[oc];
      const float* wp = w_dw3 + oc * 9;
      const float* xp = xr + (b * 64 + oc) * 256;
      #pragma unroll
      for (int ky = 0; ky < 3; ++ky) {
        int gy = h + ky - 1;
        #pragma unroll
        for (int kx = 0; kx < 3; ++kx) {
          int gx = w + kx - 1;
          float v = (gy >= 0 && gy < 16 && gx >= 0 && gx < 16) ? xp[gy * 16 + gx] : 0.f;
          f0 += wp[ky * 3 + kx] * v;
        }
      }
    } else {
      int c5 = oc - 64;
      f0 = b_dw7[c5];
      const float* wp = w_dw7 + c5 * 25;
      const float* xp = xr + (b * 64 + c5) * 256;
      #pragma unroll
      for (int ky = 0; ky < 5; ++ky) {
        int gy = h + ky - 2;
        #pragma unroll
        for (int kx = 0; kx < 5; ++kx) {
          int gx = w + kx - 2;
          float v = (gy >= 0 && gy < 16 && gx >= 0 && gx < 16) ? xp[gy * 16 + gx] : 0.f;
          f0 += wp[ky * 5 + kx] * v;
        }
      }
    }
    int pix = (b * 16 + h) * 16 + w;
    xc_bf[pix * 128 + oc] = (short)f2bf(f0 * gs[oc]);
  }
}

// =====================  k2: fused Wd-gen + dynamic conv  =====================
// Per block = 1 patch. 512 threads = 8 waves.
// Wd chunk in LDS: [256 e][32 c] bf16 = 16 KB, rows 64 B, 16-B granule XOR
// swizzle g' = q ^ ((e>>1)&3) ^ ((e>>5)&3):
//   - gen writes (e = l16*32 + j): (e>>5)&3 = l16&3 spreads lanes, 2-way max.
//   - consume b128 reads (e = wave*32+et*16+l16): (e>>1)&3 = (l16>>1)&3
//     spreads lanes to the optimal 8 lanes / 16-B column.
__global__ __launch_bounds__(512, 4) void k2_fused(
    const float* __restrict__ y, const short* __restrict__ wlin_bf,
    const short* __restrict__ xc_bf, const float* __restrict__ b_lin,
    float* __restrict__ out)
{
  __shared__ __align__(16) short Ylds[16384];   // [pix][256c] bf16, swizzled
  __shared__ __align__(16) float scratch[8192]; // staging; aliased as Wd dbuf
  short* wdlds = (short*)scratch;               // [2][256 e][32 c] bf16

  int phys = blockIdx.x;
  int blk = (phys & 7) * 64 + (phys >> 3);      // XCD-contiguous patches
  int b = blk >> 8, f = (blk >> 4) & 15, g = blk & 15;
  int tid = threadIdx.x;
  int wave = tid >> 6, lane = tid & 63;
  int quad = lane >> 4, l16 = lane & 15;

  const float* yb = y + b * 4194304 + (f * 8) * 128 + g * 8;

  // ---- stage Y: 2 super-chunks of 128 channels ----
  int c32 = tid >> 4, pf = tid & 15;            // 32 c x 16 pixel-float4
  for (int sch = 0; sch < 2; ++sch) {
    float4 v[4];
    #pragma unroll
    for (int it = 0; it < 4; ++it)
      v[it] = *(const float4*)(yb + (sch * 128 + it * 32 + c32) * 16384 + (pf >> 1) * 128 + (pf & 1) * 4);
    #pragma unroll
    for (int it = 0; it < 4; ++it)
      *(float4*)&scratch[(it * 32 + c32) * 64 + pf * 4] = v[it];
    __syncthreads();
    #pragma unroll
    for (int tt = 0; tt < 2; ++tt) {
      int task = tt * 512 + tid;
      int pix = task & 63, cg = task >> 6;      // 64 pix x 16 c-groups of 8
      float s0 = scratch[(cg * 8 + 0) * 64 + pix];
      float s1 = scratch[(cg * 8 + 1) * 64 + pix];
      float s2 = scratch[(cg * 8 + 2) * 64 + pix];
      float s3 = scratch[(cg * 8 + 3) * 64 + pix];
      float s4 = scratch[(cg * 8 + 4) * 64 + pix];
      float s5 = scratch[(cg * 8 + 5) * 64 + pix];
      float s6 = scratch[(cg * 8 + 6) * 64 + pix];
      float s7 = scratch[(cg * 8 + 7) * 64 + pix];
      uint4 pk;
      pk.x = pk2bf(s0, s1); pk.y = pk2bf(s2, s3);
      pk.z = pk2bf(s4, s5); pk.w = pk2bf(s6, s7);
      int chunk = sch * 16 + cg;                // 8-ch group id [0,32)
      int physc = chunk ^ (pix & 7);
      *(uint4*)&Ylds[pix * 256 + physc * 8] = pk;
    }
    __syncthreads();
  }

  // ---- xc B-fragment: B[k=i][n=g] = xc[pix][g*16+i], constant over chunks ----
  short8 bx = {0, 0, 0, 0, 0, 0, 0, 0};
  if (quad < 2 && l16 < 8)
    bx = *(const short8*)(xc_bf + blk * 128 + l16 * 16 + quad * 8);

  f32x4 zero4 = {0.f, 0.f, 0.f, 0.f};
  f32x4 acc[2][4];
  #pragma unroll
  for (int et = 0; et < 2; ++et)
    #pragma unroll
    for (int nt = 0; nt < 4; ++nt)
      acc[et][nt] = zero4;

  // ---- generator for one 256e x 32c chunk (8 MFMA / wave) ----
  // A[m=l16 -> c offset][k] = wlin[(j*256 + c0 + l16)*16 + k]  (L2-resident)
  // D[row=quad*4+r -> c][col=l16 -> g]: lane packs 4 consecutive c of row
  // e = l16*32 + j  ->  one ds_write_b64.
  auto gen_chunk = [&](int cc, int buf) {
    short* dst = wdlds + buf * 8192;
    #pragma unroll
    for (int jj = 0; jj < 4; ++jj) {
      int j = wave * 4 + jj;
      #pragma unroll
      for (int hh = 0; hh < 2; ++hh) {
        int c0 = cc * 32 + hh * 16;
        short8 aw = {0, 0, 0, 0, 0, 0, 0, 0};
        if (quad < 2)
          aw = *(const short8*)(wlin_bf + (j * 256 + c0 + l16) * 16 + quad * 8);
        f32x4 d = __builtin_amdgcn_mfma_f32_16x16x32_bf16(aw, bx, zero4, 0, 0, 0);
        if (l16 < 8) {
          int e = l16 * 32 + j;
          float4 bl = *(const float4*)(b_lin + j * 256 + c0 + quad * 4);
          uint2 pk;
          pk.x = pk2bf(d[0] + bl.x, d[1] + bl.y);
          pk.y = pk2bf(d[2] + bl.z, d[3] + bl.w);
          int q16 = hh * 2 + (quad >> 1);
          int sw = q16 ^ ((e >> 1) & 3) ^ ((e >> 5) & 3);
          *(uint2*)&dst[e * 32 + sw * 8 + (quad & 1) * 4] = pk;
        }
      }
    }
  };

  gen_chunk(0, 0);
  __syncthreads();

  // ---- K-loop: 8 chunks of 32 channels, gen(cc+1) overlapped with use(cc) ----
  for (int cc = 0; cc < 8; ++cc) {
    if (cc < 7) gen_chunk(cc + 1, (cc + 1) & 1);

    const short* src = wdlds + (cc & 1) * 8192;
    short8 A2[2], Bf[4];
    #pragma unroll
    for (int et = 0; et < 2; ++et) {
      int e = wave * 32 + et * 16 + l16;
      int sw = quad ^ ((e >> 1) & 3) ^ ((e >> 5) & 3);
      A2[et] = *(const short8*)&src[e * 32 + sw * 8];
    }
    int chunkY = cc * 4 + quad;
    #pragma unroll
    for (int nt = 0; nt < 4; ++nt) {
      int nn = nt * 16 + l16;
      int physc = chunkY ^ (nn & 7);
      Bf[nt] = *(const short8*)&Ylds[nn * 256 + physc * 8];
    }
    #pragma unroll
    for (int et = 0; et < 2; ++et)
      #pragma unroll
      for (int nt = 0; nt < 4; ++nt)
        acc[et][nt] = __builtin_amdgcn_mfma_f32_16x16x32_bf16(A2[et], Bf[nt], acc[et][nt], 0, 0, 0);
    __syncthreads();
  }

  // ---- epilogue: D row=quad*4+r -> e, col=l16 -> pix ----
  float* ob = out + b * 4194304 + (f * 8) * 128 + g * 8;
  #pragma unroll
  for (int et = 0; et < 2; ++et) {
    int e0 = wave * 32 + et * 16 + quad * 4;
    #pragma unroll
    for (int nt = 0; nt < 4; ++nt) {
      int pix = nt * 16 + l16;
      float* oa = ob + (pix >> 3) * 128 + (pix & 7);
      #pragma unroll
      for (int r = 0; r < 4; ++r)
        oa[(e0 + r) * 16384] = acc[et][nt][r];
    }
  }
}

// ============================  launcher  ============================
extern "C" void kernel_launch(void* const* d_in, const int* in_sizes, int n_in,
                              void* d_out, int out_size, void* d_ws, size_t ws_size,
                              hipStream_t stream) {
  const float* x        = (const float*)d_in[0];
  const float* y        = (const float*)d_in[1];
  const float* w_cr     = (const float*)d_in[2];
  const float* b_cr     = (const float*)d_in[3];
  const float* w_dw3    = (const float*)d_in[4];
  const float* b_dw3    = (const float*)d_in[5];
  const float* w_dw7    = (const float*)d_in[6];
  const float* b_dw7    = (const float*)d_in[7];
  const float* w_gate   = (const float*)d_in[8];
  const float* b_gate   = (const float*)d_in[9];
  const float* bn_gamma = (const float*)d_in[10];
  const float* bn_beta  = (const float*)d_in[11];
  const float* bn_mean  = (const float*)d_in[12];
  const float* bn_var   = (const float*)d_in[13];
  const float* sr_scale = (const float*)d_in[14];
  const float* sr_bias  = (const float*)d_in[15];
  const float* w_lin    = (const float*)d_in[16];
  const float* b_lin    = (const float*)d_in[17];
  float* out = (float*)d_out;

  // ws layout: xc_bf 128KB | wlin_bf 256KB | xr 128KB   (Wd eliminated)
  short* xc_bf   = (short*)d_ws;
  short* wlin_bf = (short*)((char*)d_ws + 131072);
  float* xr      = (float*)((char*)d_ws + 131072 + 262144);

  hipLaunchKernelGGL(k1a_groupconv, dim3(128), dim3(256), 0, stream, x, w_cr, b_cr, xr);
  hipLaunchKernelGGL(k1b_gate_dw, dim3(512), dim3(256), 0, stream,
                     x, xr, w_dw3, b_dw3, w_dw7, b_dw7, w_gate, b_gate,
                     bn_gamma, bn_beta, bn_mean, bn_var, sr_scale, sr_bias,
                     w_lin, wlin_bf, xc_bf);
  hipLaunchKernelGGL(k2_fused, dim3(512), dim3(512), 0, stream,
                     y, wlin_bf, xc_bf, b_lin, out);
}

// Round 2
// 167.574 us; speedup vs baseline: 1.0048x; 1.0048x over previous
//
#include <hip/hip_runtime.h>
#include <stdint.h>

// ---------------------------------------------------------------------------
// WeightGenerator_V4, round 5.
//   k1 (merged, 640 blocks):
//     blocks 0-511  : gate (1x1 conv + BN + StarReLU) -> gs fp32, coalesced
//                     w_gate reads (4 lanes per output); also w_lin -> bf16.
//     blocks 512-639: grouped 3x3 conv + dw3 + dw5 fused in LDS -> f0 fp32
//                     (xr never touches HBM/L2 as a buffer).
//   k2 (1024 blocks = patch x e-half, 512 thr, 48 KB LDS -> 3 blocks/CU,
//       24 waves/CU):
//     per block: stage Y patch (4 rounds of 64 ch, 16 KB scratch), build
//     xc fragment from f0*gs, then 8-chunk K-loop: j-PAIRED gen MFMA
//     (full K=32: two wlin rows per MFMA) into 2x8 KB LDS dbuf, consume
//     with 16x16x32 MFMA. Gate multiply fused into fragment build.
// ---------------------------------------------------------------------------

typedef __attribute__((ext_vector_type(8))) short short8;
typedef __attribute__((ext_vector_type(4))) float f32x4;

#define BN_EPS 1e-5f

__device__ __forceinline__ unsigned short f2bf(float f) {
  unsigned u = __float_as_uint(f);
  return (unsigned short)((u + 0x8000u) >> 16);
}
__device__ __forceinline__ unsigned pk2bf(float a, float b) {
  unsigned ua = __float_as_uint(a), ub = __float_as_uint(b);
  return ((ua + 0x8000u) >> 16) | ((ub + 0x8000u) & 0xFFFF0000u);
}

// =====================  k1: gate + conv/dw (role-split)  =====================
__global__ __launch_bounds__(256) void k1_merged(
    const float* __restrict__ x, const float* __restrict__ w_cr,
    const float* __restrict__ b_cr, const float* __restrict__ w_dw3,
    const float* __restrict__ b_dw3, const float* __restrict__ w_dw7,
    const float* __restrict__ b_dw7, const float* __restrict__ w_gate,
    const float* __restrict__ b_gate, const float* __restrict__ bn_gamma,
    const float* __restrict__ bn_beta, const float* __restrict__ bn_mean,
    const float* __restrict__ bn_var, const float* __restrict__ sr_scale,
    const float* __restrict__ sr_bias, const float* __restrict__ w_lin,
    short* __restrict__ wlin_bf, float* __restrict__ f0_out,
    float* __restrict__ gs_out)
{
  __shared__ __align__(16) float xcen[256];   // gate role
  __shared__ __align__(16) float xs[4][256];  // conv role
  __shared__ __align__(16) float xrs[256];    // conv role

  int blk = blockIdx.x;
  int t = threadIdx.x;

  if (blk < 512) {
    // ---------------- gate role: one pixel per block ----------------
    int b = blk >> 8, h = (blk >> 4) & 15, w = blk & 15;
    int pix = (b * 16 + h) * 16 + w;

    { int idx = blk * 256 + t; wlin_bf[idx] = (short)f2bf(w_lin[idx]); }

    xcen[t] = x[b * 65536 + t * 256 + h * 16 + w];
    __syncthreads();

    int wave = t >> 6, lane = t & 63;
    int oq = lane >> 2, ol = lane & 3;          // 16 outputs x 4 lanes
    const float4* wg4 = (const float4*)w_gate;
    const float4* xc4 = (const float4*)xcen;
    float ss = sr_scale[0], sb = sr_bias[0];

    #pragma unroll
    for (int pass = 0; pass < 2; ++pass) {
      int o = wave * 32 + pass * 16 + oq;       // [0,128)
      float acc = 0.f;
      #pragma unroll
      for (int k = 0; k < 16; ++k) {
        int j = k * 4 + ol;                     // float4 index over 256 ch
        float4 wv = wg4[o * 64 + j];            // quad-coalesced 64B lines
        float4 xv = xc4[j];                     // LDS broadcast
        acc += wv.x * xv.x + wv.y * xv.y + wv.z * xv.z + wv.w * xv.w;
      }
      acc += __shfl_xor(acc, 1);
      acc += __shfl_xor(acc, 2);
      float inv = bn_gamma[o] * rsqrtf(bn_var[o] + BN_EPS);
      float gg = (acc + b_gate[o] - bn_mean[o]) * inv + bn_beta[o];
      gg = fmaxf(gg, 0.f);
      gg = ss * gg * gg + sb;
      if (ol == 0) gs_out[pix * 128 + o] = gg;
    }
  } else {
    // ---------------- conv role: one (b, cr) channel-image ----------------
    int cb = blk - 512;
    int b = cb >> 6, cr = cb & 63;
    {
      int ch = t >> 6, off = (t & 63) * 4;
      float4 v = *(const float4*)(x + b * 65536 + (cr * 4 + ch) * 256 + off);
      *(float4*)&xs[ch][off] = v;
    }
    __syncthreads();
    int h = t >> 4, w = t & 15;
    float a = b_cr[cr];
    #pragma unroll
    for (int ii = 0; ii < 4; ++ii) {
      const float* wp = w_cr + (cr * 4 + ii) * 9;
      #pragma unroll
      for (int ky = 0; ky < 3; ++ky) {
        int gy = h + ky - 1;
        #pragma unroll
        for (int kx = 0; kx < 3; ++kx) {
          int gx = w + kx - 1;
          float v = (gy >= 0 && gy < 16 && gx >= 0 && gx < 16) ? xs[ii][gy * 16 + gx] : 0.f;
          a += wp[ky * 3 + kx] * v;
        }
      }
    }
    xrs[t] = a;
    __syncthreads();

    float f3 = b_dw3[cr];
    {
      const float* wp = w_dw3 + cr * 9;
      #pragma unroll
      for (int ky = 0; ky < 3; ++ky) {
        int gy = h + ky - 1;
        #pragma unroll
        for (int kx = 0; kx < 3; ++kx) {
          int gx = w + kx - 1;
          float v = (gy >= 0 && gy < 16 && gx >= 0 && gx < 16) ? xrs[gy * 16 + gx] : 0.f;
          f3 += wp[ky * 3 + kx] * v;
        }
      }
    }
    float f5 = b_dw7[cr];
    {
      const float* wp = w_dw7 + cr * 25;
      #pragma unroll
      for (int ky = 0; ky < 5; ++ky) {
        int gy = h + ky - 2;
        #pragma unroll
        for (int kx = 0; kx < 5; ++kx) {
          int gx = w + kx - 2;
          float v = (gy >= 0 && gy < 16 && gx >= 0 && gx < 16) ? xrs[gy * 16 + gx] : 0.f;
          f5 += wp[ky * 5 + kx] * v;
        }
      }
    }
    int pix = (b * 16 + h) * 16 + w;
    f0_out[pix * 128 + cr] = f3;
    f0_out[pix * 128 + 64 + cr] = f5;
  }
}

// =====================  k2: fused Wd-gen + dynamic conv (e-split)  ==========
// Block = (patch, e-half). 512 threads = 8 waves, each owns 16 e-rows.
// LDS 48 KB: Ylds 32 KB + 16 KB union(stage scratch, Wd double buffer).
// Wd chunk: [128 e][32 c] bf16, rows 64 B, 16-B granule XOR swizzle
//   slot(gi) = gi ^ ((e>>1)&3) ^ ((e>>5)&3)
//   gen writes uint2 (half-granule), consume reads b128 (one granule) --
//   verified <=2-way write, 8-cycle-optimal read.
__global__ __launch_bounds__(512, 6) void k2_fused(
    const float* __restrict__ y, const short* __restrict__ wlin_bf,
    const float* __restrict__ f0_in, const float* __restrict__ gs_in,
    const float* __restrict__ b_lin, float* __restrict__ out)
{
  __shared__ __align__(16) short Ylds[16384];   // [pix][256c] bf16, swizzled
  __shared__ __align__(16) char dyn[16384];     // scratch (stage) / Wd dbuf
  float* scratch = (float*)dyn;                 // [64c][64pix] fp32 per round
  short* wdbuf = (short*)dyn;                   // [2][128 e][32 c] bf16

  int phys = blockIdx.x;
  int logical = (phys & 7) * 128 + (phys >> 3); // XCD-contiguous
  int patch = logical >> 1, ehalf = logical & 1;
  int b = patch >> 8, f = (patch >> 4) & 15, g = patch & 15;
  int gbase = ehalf * 4;
  int tid = threadIdx.x;
  int wave = tid >> 6, lane = tid & 63;
  int quad = lane >> 4, l16 = lane & 15;

  const float* yb = y + b * 4194304 + (f * 8) * 128 + g * 8;

  // ---- stage Y: 4 rounds of 64 channels (16 KB scratch) ----
  int c32 = tid >> 4, pf = tid & 15;            // 32 c x 16 pixel-float4
  for (int sch = 0; sch < 4; ++sch) {
    float4 v[2];
    #pragma unroll
    for (int it = 0; it < 2; ++it)
      v[it] = *(const float4*)(yb + (sch * 64 + it * 32 + c32) * 16384 + (pf >> 1) * 128 + (pf & 1) * 4);
    #pragma unroll
    for (int it = 0; it < 2; ++it)
      *(float4*)&scratch[(it * 32 + c32) * 64 + pf * 4] = v[it];
    __syncthreads();
    {
      int pix = tid & 63, cg = tid >> 6;        // 64 pix x 8 c-groups of 8
      float s0 = scratch[(cg * 8 + 0) * 64 + pix];
      float s1 = scratch[(cg * 8 + 1) * 64 + pix];
      float s2 = scratch[(cg * 8 + 2) * 64 + pix];
      float s3 = scratch[(cg * 8 + 3) * 64 + pix];
      float s4 = scratch[(cg * 8 + 4) * 64 + pix];
      float s5 = scratch[(cg * 8 + 5) * 64 + pix];
      float s6 = scratch[(cg * 8 + 6) * 64 + pix];
      float s7 = scratch[(cg * 8 + 7) * 64 + pix];
      uint4 pk;
      pk.x = pk2bf(s0, s1); pk.y = pk2bf(s2, s3);
      pk.z = pk2bf(s4, s5); pk.w = pk2bf(s6, s7);
      int chunk = sch * 8 + cg;                 // 8-ch group id [0,32)
      int physc = chunk ^ (pix & 7);
      *(uint4*)&Ylds[pix * 256 + physc * 8] = pk;
    }
    __syncthreads();
  }

  // ---- xc fragment (f0*gs -> bf16), constant over chunks ----
  // B[n][k]: n = jsel*8 + geff (geff<4 used), value = xc[gbase+geff][k%16]
  // iff (n>>3) == (k>>4).
  int geff = l16 & 7, jsel = l16 >> 3;
  bool bvalid = (geff < 4) && (jsel == (quad >> 1));
  short8 bx = {0, 0, 0, 0, 0, 0, 0, 0};
  if (bvalid) {
    const float* fp = f0_in + patch * 128 + (gbase + geff) * 16 + (quad & 1) * 8;
    const float* gp = gs_in + patch * 128 + (gbase + geff) * 16 + (quad & 1) * 8;
    float4 fa = *(const float4*)fp, fb = *(const float4*)(fp + 4);
    float4 ga = *(const float4*)gp, gb = *(const float4*)(gp + 4);
    bx[0] = (short)f2bf(fa.x * ga.x); bx[1] = (short)f2bf(fa.y * ga.y);
    bx[2] = (short)f2bf(fa.z * ga.z); bx[3] = (short)f2bf(fa.w * ga.w);
    bx[4] = (short)f2bf(fb.x * gb.x); bx[5] = (short)f2bf(fb.y * gb.y);
    bx[6] = (short)f2bf(fb.z * gb.z); bx[7] = (short)f2bf(fb.w * gb.w);
  }

  f32x4 zero4 = {0.f, 0.f, 0.f, 0.f};
  f32x4 acc[4];
  #pragma unroll
  for (int nt = 0; nt < 4; ++nt) acc[nt] = zero4;

  // ---- j-paired generator for one 128e x 32c chunk (4 MFMA / wave) ----
  // A[m=l16 -> c][k]: k<16 from wlin row j0=jp*2, k>=16 from j1=jp*2+1.
  // D[row=quad*4+r -> c][col=l16 -> (jsel,geff)]; e_local = geff*32+jp*2+jsel.
  int jA_half = quad >> 1;                      // which j of the pair A feeds
  auto gen_chunk = [&](int cc, int buf) {
    short* dst = wdbuf + buf * 4096;
    #pragma unroll
    for (int jj = 0; jj < 2; ++jj) {
      int jp = wave * 2 + jj;                   // [0,16)
      int jA = jp * 2 + jA_half;
      int jD = jp * 2 + jsel;
      #pragma unroll
      for (int hh = 0; hh < 2; ++hh) {
        int c0 = cc * 32 + hh * 16;
        short8 aw = *(const short8*)(wlin_bf + (jA * 256 + c0 + l16) * 16 + (quad & 1) * 8);
        f32x4 d = __builtin_amdgcn_mfma_f32_16x16x32_bf16(aw, bx, zero4, 0, 0, 0);
        if (geff < 4) {
          int e = geff * 32 + jD;               // e_local in [0,128)
          float4 bl = *(const float4*)(b_lin + jD * 256 + c0 + quad * 4);
          uint2 pk;
          pk.x = pk2bf(d[0] + bl.x, d[1] + bl.y);
          pk.y = pk2bf(d[2] + bl.z, d[3] + bl.w);
          int q16 = hh * 2 + (quad >> 1);
          int sw = q16 ^ ((e >> 1) & 3) ^ ((e >> 5) & 3);
          *(uint2*)&dst[e * 32 + sw * 8 + (quad & 1) * 4] = pk;
        }
      }
    }
  };

  gen_chunk(0, 0);
  __syncthreads();

  // ---- K-loop: 8 chunks of 32 channels, gen(cc+1) overlapped with use(cc) ----
  for (int cc = 0; cc < 8; ++cc) {
    if (cc < 7) gen_chunk(cc + 1, (cc + 1) & 1);

    const short* src = wdbuf + (cc & 1) * 4096;
    short8 A2, Bf[4];
    {
      int e = wave * 16 + l16;
      int sw = quad ^ ((e >> 1) & 3) ^ ((e >> 5) & 3);
      A2 = *(const short8*)&src[e * 32 + sw * 8];
    }
    int chunkY = cc * 4 + quad;
    #pragma unroll
    for (int nt = 0; nt < 4; ++nt) {
      int nn = nt * 16 + l16;
      int physc = chunkY ^ (nn & 7);
      Bf[nt] = *(const short8*)&Ylds[nn * 256 + physc * 8];
    }
    #pragma unroll
    for (int nt = 0; nt < 4; ++nt)
      acc[nt] = __builtin_amdgcn_mfma_f32_16x16x32_bf16(A2, Bf[nt], acc[nt], 0, 0, 0);
    __syncthreads();
  }

  // ---- epilogue: D row=quad*4+r -> e, col=l16 -> pix ----
  float* ob = out + b * 4194304 + (f * 8) * 128 + g * 8;
  int e0 = ehalf * 128 + wave * 16 + quad * 4;
  #pragma unroll
  for (int nt = 0; nt < 4; ++nt) {
    int pix = nt * 16 + l16;
    float* oa = ob + (pix >> 3) * 128 + (pix & 7);
    #pragma unroll
    for (int r = 0; r < 4; ++r)
      oa[(e0 + r) * 16384] = acc[nt][r];
  }
}

// ============================  launcher  ============================
extern "C" void kernel_launch(void* const* d_in, const int* in_sizes, int n_in,
                              void* d_out, int out_size, void* d_ws, size_t ws_size,
                              hipStream_t stream) {
  const float* x        = (const float*)d_in[0];
  const float* y        = (const float*)d_in[1];
  const float* w_cr     = (const float*)d_in[2];
  const float* b_cr     = (const float*)d_in[3];
  const float* w_dw3    = (const float*)d_in[4];
  const float* b_dw3    = (const float*)d_in[5];
  const float* w_dw7    = (const float*)d_in[6];
  const float* b_dw7    = (const float*)d_in[7];
  const float* w_gate   = (const float*)d_in[8];
  const float* b_gate   = (const float*)d_in[9];
  const float* bn_gamma = (const float*)d_in[10];
  const float* bn_beta  = (const float*)d_in[11];
  const float* bn_mean  = (const float*)d_in[12];
  const float* bn_var   = (const float*)d_in[13];
  const float* sr_scale = (const float*)d_in[14];
  const float* sr_bias  = (const float*)d_in[15];
  const float* w_lin    = (const float*)d_in[16];
  const float* b_lin    = (const float*)d_in[17];
  float* out = (float*)d_out;

  // ws layout: f0 256KB | gs 256KB | wlin_bf 256KB
  float* f0      = (float*)d_ws;
  float* gs      = (float*)((char*)d_ws + 262144);
  short* wlin_bf = (short*)((char*)d_ws + 524288);

  hipLaunchKernelGGL(k1_merged, dim3(640), dim3(256), 0, stream,
                     x, w_cr, b_cr, w_dw3, b_dw3, w_dw7, b_dw7, w_gate, b_gate,
                     bn_gamma, bn_beta, bn_mean, bn_var, sr_scale, sr_bias,
                     w_lin, wlin_bf, f0, gs);
  hipLaunchKernelGGL(k2_fused, dim3(1024), dim3(512), 0, stream,
                     y, wlin_bf, f0, gs, b_lin, out);
}

// Round 3
// 152.956 us; speedup vs baseline: 1.1008x; 1.0956x over previous
//
#include <hip/hip_runtime.h>
#include <stdint.h>

// ---------------------------------------------------------------------------
// WeightGenerator_V4, round 6: latency-restructured fused k2.
//   k1 (unchanged from r5, known-good): gate -> gs; conv+dw3/dw5 -> f0;
//      w_lin -> bf16.
//   k2: 512 blocks (1 patch each), 512 thr, 64 KB LDS -> 2 blocks/CU,
//      exactly one dispatch round.
//      - ALL y loads issued upfront into regs (staging rounds are pure-LDS,
//        HBM latency exposed once, not 4x).
//      - j-paired full-K gen (4 MFMA/wave/chunk, full D utilization),
//        b_lin folded into MFMA C-operand.
//      - 2-deep register prefetch of wlin fragments across the K-loop.
//      - swizzles re-derived: gen-write 4/bank opt, A2 8/bank opt,
//        Bf physc = chunk^(pix&15) 8/bank opt, scratch [64][65] 2-way free.
// ---------------------------------------------------------------------------

typedef __attribute__((ext_vector_type(8))) short short8;
typedef __attribute__((ext_vector_type(4))) float f32x4;

#define BN_EPS 1e-5f

__device__ __forceinline__ unsigned short f2bf(float f) {
  unsigned u = __float_as_uint(f);
  return (unsigned short)((u + 0x8000u) >> 16);
}
__device__ __forceinline__ unsigned pk2bf(float a, float b) {
  unsigned ua = __float_as_uint(a), ub = __float_as_uint(b);
  return ((ua + 0x8000u) >> 16) | ((ub + 0x8000u) & 0xFFFF0000u);
}

// =====================  k1: gate + conv/dw (role-split)  =====================
__global__ __launch_bounds__(256) void k1_merged(
    const float* __restrict__ x, const float* __restrict__ w_cr,
    const float* __restrict__ b_cr, const float* __restrict__ w_dw3,
    const float* __restrict__ b_dw3, const float* __restrict__ w_dw7,
    const float* __restrict__ b_dw7, const float* __restrict__ w_gate,
    const float* __restrict__ b_gate, const float* __restrict__ bn_gamma,
    const float* __restrict__ bn_beta, const float* __restrict__ bn_mean,
    const float* __restrict__ bn_var, const float* __restrict__ sr_scale,
    const float* __restrict__ sr_bias, const float* __restrict__ w_lin,
    short* __restrict__ wlin_bf, float* __restrict__ f0_out,
    float* __restrict__ gs_out)
{
  __shared__ __align__(16) float xcen[256];   // gate role
  __shared__ __align__(16) float xs[4][256];  // conv role
  __shared__ __align__(16) float xrs[256];    // conv role

  int blk = blockIdx.x;
  int t = threadIdx.x;

  if (blk < 512) {
    // ---------------- gate role: one pixel per block ----------------
    int b = blk >> 8, h = (blk >> 4) & 15, w = blk & 15;
    int pix = (b * 16 + h) * 16 + w;

    { int idx = blk * 256 + t; wlin_bf[idx] = (short)f2bf(w_lin[idx]); }

    xcen[t] = x[b * 65536 + t * 256 + h * 16 + w];
    __syncthreads();

    int wave = t >> 6, lane = t & 63;
    int oq = lane >> 2, ol = lane & 3;          // 16 outputs x 4 lanes
    const float4* wg4 = (const float4*)w_gate;
    const float4* xc4 = (const float4*)xcen;
    float ss = sr_scale[0], sb = sr_bias[0];

    #pragma unroll
    for (int pass = 0; pass < 2; ++pass) {
      int o = wave * 32 + pass * 16 + oq;       // [0,128)
      float acc = 0.f;
      #pragma unroll
      for (int k = 0; k < 16; ++k) {
        int j = k * 4 + ol;                     // float4 index over 256 ch
        float4 wv = wg4[o * 64 + j];            // quad-coalesced 64B lines
        float4 xv = xc4[j];                     // LDS broadcast
        acc += wv.x * xv.x + wv.y * xv.y + wv.z * xv.z + wv.w * xv.w;
      }
      acc += __shfl_xor(acc, 1);
      acc += __shfl_xor(acc, 2);
      float inv = bn_gamma[o] * rsqrtf(bn_var[o] + BN_EPS);
      float gg = (acc + b_gate[o] - bn_mean[o]) * inv + bn_beta[o];
      gg = fmaxf(gg, 0.f);
      gg = ss * gg * gg + sb;
      if (ol == 0) gs_out[pix * 128 + o] = gg;
    }
  } else {
    // ---------------- conv role: one (b, cr) channel-image ----------------
    int cb = blk - 512;
    int b = cb >> 6, cr = cb & 63;
    {
      int ch = t >> 6, off = (t & 63) * 4;
      float4 v = *(const float4*)(x + b * 65536 + (cr * 4 + ch) * 256 + off);
      *(float4*)&xs[ch][off] = v;
    }
    __syncthreads();
    int h = t >> 4, w = t & 15;
    float a = b_cr[cr];
    #pragma unroll
    for (int ii = 0; ii < 4; ++ii) {
      const float* wp = w_cr + (cr * 4 + ii) * 9;
      #pragma unroll
      for (int ky = 0; ky < 3; ++ky) {
        int gy = h + ky - 1;
        #pragma unroll
        for (int kx = 0; kx < 3; ++kx) {
          int gx = w + kx - 1;
          float v = (gy >= 0 && gy < 16 && gx >= 0 && gx < 16) ? xs[ii][gy * 16 + gx] : 0.f;
          a += wp[ky * 3 + kx] * v;
        }
      }
    }
    xrs[t] = a;
    __syncthreads();

    float f3 = b_dw3[cr];
    {
      const float* wp = w_dw3 + cr * 9;
      #pragma unroll
      for (int ky = 0; ky < 3; ++ky) {
        int gy = h + ky - 1;
        #pragma unroll
        for (int kx = 0; kx < 3; ++kx) {
          int gx = w + kx - 1;
          float v = (gy >= 0 && gy < 16 && gx >= 0 && gx < 16) ? xrs[gy * 16 + gx] : 0.f;
          f3 += wp[ky * 3 + kx] * v;
        }
      }
    }
    float f5 = b_dw7[cr];
    {
      const float* wp = w_dw7 + cr * 25;
      #pragma unroll
      for (int ky = 0; ky < 5; ++ky) {
        int gy = h + ky - 2;
        #pragma unroll
        for (int kx = 0; kx < 5; ++kx) {
          int gx = w + kx - 2;
          float v = (gy >= 0 && gy < 16 && gx >= 0 && gx < 16) ? xrs[gy * 16 + gx] : 0.f;
          f5 += wp[ky * 5 + kx] * v;
        }
      }
    }
    int pix = (b * 16 + h) * 16 + w;
    f0_out[pix * 128 + cr] = f3;
    f0_out[pix * 128 + 64 + cr] = f5;
  }
}

// =====================  k2: fused Wd-gen + dynamic conv  =====================
// 512 blocks = 1 patch each. 512 threads = 8 waves (32 e-rows each).
// LDS 64 KB: Ylds 32 KB + dyn 32 KB (stage scratch [64][65] f32 16.6 KB
// aliased with Wd dbuf [2][256e][32c] bf16 32 KB).
__global__ __launch_bounds__(512, 4) void k2_fused(
    const float* __restrict__ y, const short* __restrict__ wlin_bf,
    const float* __restrict__ f0_in, const float* __restrict__ gs_in,
    const float* __restrict__ b_lin, float* __restrict__ out)
{
  __shared__ __align__(16) short Ylds[16384];   // [pix][32 granules of 8c]
  __shared__ __align__(16) char dyn[32768];
  float* scratch = (float*)dyn;                 // [64 c][65] f32
  short* wdbuf = (short*)dyn;                   // [2][256 e][32 c] bf16

  int phys = blockIdx.x;
  int blk = (phys & 7) * 64 + (phys >> 3);      // XCD-contiguous patches
  int b = blk >> 8, f = (blk >> 4) & 15, g = blk & 15;
  int tid = threadIdx.x;
  int wave = tid >> 6, lane = tid & 63;
  int quad = lane >> 4, l16 = lane & 15;
  int geff = l16 & 7, jsel = l16 >> 3;

  const float* yb = y + b * 4194304 + (f * 8) * 128 + g * 8;

  // ---- issue ALL y loads upfront: 8 float4/thread, one exposed latency ----
  int c32 = tid >> 4, pf = tid & 15;            // 32 c x 16 pixel-float4
  float4 yv[4][2];
  #pragma unroll
  for (int sch = 0; sch < 4; ++sch)
    #pragma unroll
    for (int it = 0; it < 2; ++it)
      yv[sch][it] = *(const float4*)(yb + (sch * 64 + it * 32 + c32) * 16384 + (pf >> 1) * 128 + (pf & 1) * 4);

  // ---- issue wlin prefetch for chunks 0,1 (slot = chunk&1) ----
  short8 aw[2][2][2];                           // [slot][jj][hh]
  #pragma unroll
  for (int s = 0; s < 2; ++s)
    #pragma unroll
    for (int jj = 0; jj < 2; ++jj) {
      int jA = (wave * 2 + jj) * 2 + (quad >> 1);
      #pragma unroll
      for (int hh = 0; hh < 2; ++hh) {
        int c0 = s * 32 + hh * 16;
        aw[s][jj][hh] = *(const short8*)(wlin_bf + (jA * 256 + c0 + l16) * 16 + (quad & 1) * 8);
      }
    }

  // ---- issue f0/gs loads (packed into bx after staging) ----
  bool bval = (jsel == (quad >> 1));
  const float* fp = f0_in + blk * 128 + geff * 16 + (quad & 1) * 8;
  const float* gp = gs_in + blk * 128 + geff * 16 + (quad & 1) * 8;
  float4 f0a = *(const float4*)fp, f0b = *(const float4*)(fp + 4);
  float4 gsa = *(const float4*)gp, gsb = *(const float4*)(gp + 4);

  // ---- stage Y: 4 pure-LDS rounds of 64 channels ----
  #pragma unroll
  for (int sch = 0; sch < 4; ++sch) {
    #pragma unroll
    for (int it = 0; it < 2; ++it)
      *(float4*)&scratch[(it * 32 + c32) * 65 + pf * 4] = yv[sch][it];
    __syncthreads();
    {
      int pix = tid & 63, cg = tid >> 6;        // 64 pix x 8 c-groups of 8
      float s0 = scratch[(cg * 8 + 0) * 65 + pix];
      float s1 = scratch[(cg * 8 + 1) * 65 + pix];
      float s2 = scratch[(cg * 8 + 2) * 65 + pix];
      float s3 = scratch[(cg * 8 + 3) * 65 + pix];
      float s4 = scratch[(cg * 8 + 4) * 65 + pix];
      float s5 = scratch[(cg * 8 + 5) * 65 + pix];
      float s6 = scratch[(cg * 8 + 6) * 65 + pix];
      float s7 = scratch[(cg * 8 + 7) * 65 + pix];
      uint4 pk;
      pk.x = pk2bf(s0, s1); pk.y = pk2bf(s2, s3);
      pk.z = pk2bf(s4, s5); pk.w = pk2bf(s6, s7);
      int chunk = sch * 8 + cg;                 // 8-ch group id [0,32)
      int physc = chunk ^ (pix & 15);           // read-optimal swizzle
      *(uint4*)&Ylds[pix * 256 + physc * 8] = pk;
    }
    __syncthreads();
  }

  // ---- xc fragment: B[k][n=jsel*8+geff] = xc[geff][k%16] iff k>>4==jsel ----
  short8 bx = {0, 0, 0, 0, 0, 0, 0, 0};
  if (bval) {
    bx[0] = (short)f2bf(f0a.x * gsa.x); bx[1] = (short)f2bf(f0a.y * gsa.y);
    bx[2] = (short)f2bf(f0a.z * gsa.z); bx[3] = (short)f2bf(f0a.w * gsa.w);
    bx[4] = (short)f2bf(f0b.x * gsb.x); bx[5] = (short)f2bf(f0b.y * gsb.y);
    bx[6] = (short)f2bf(f0b.z * gsb.z); bx[7] = (short)f2bf(f0b.w * gsb.w);
  }

  f32x4 acc[2][4];
  #pragma unroll
  for (int et = 0; et < 2; ++et)
    #pragma unroll
    for (int nt = 0; nt < 4; ++nt)
      acc[et][nt] = {0.f, 0.f, 0.f, 0.f};

  // ---- j-paired generator: 256e x 32c chunk, 4 MFMA/wave, bias in C-in ----
  // A[m=l16->c][k]: k-half (quad>>1) selects wlin row jA = jp*2+(quad>>1).
  // D[row=quad*4+r -> c][col=l16 -> (jsel,geff)]; e = geff*32 + jp*2 + jsel.
  auto gen_chunk = [&](int cc, int buf, int slot) {
    short* dst = wdbuf + buf * 8192;
    #pragma unroll
    for (int jj = 0; jj < 2; ++jj) {
      int jp = wave * 2 + jj;
      int jD = jp * 2 + jsel;
      #pragma unroll
      for (int hh = 0; hh < 2; ++hh) {
        int c0 = cc * 32 + hh * 16;
        float4 bl = *(const float4*)(b_lin + jD * 256 + c0 + quad * 4);
        f32x4 cin = {bl.x, bl.y, bl.z, bl.w};
        f32x4 d = __builtin_amdgcn_mfma_f32_16x16x32_bf16(aw[slot][jj][hh], bx, cin, 0, 0, 0);
        int e = geff * 32 + jD;
        uint2 pk;
        pk.x = pk2bf(d[0], d[1]);
        pk.y = pk2bf(d[2], d[3]);
        int q16 = hh * 2 + (quad >> 1);
        int sw = q16 ^ ((e >> 1) & 3) ^ ((e >> 5) & 3);
        *(uint2*)&dst[e * 32 + sw * 8 + (quad & 1) * 4] = pk;
      }
    }
  };

  gen_chunk(0, 0, 0);
  __syncthreads();

  // ---- K-loop: 8 chunks; gen(cc+1) + wlin-prefetch(cc+2) overlap use(cc) ----
  #pragma unroll
  for (int cc = 0; cc < 8; ++cc) {
    if (cc < 6) {                               // prefetch wlin for chunk cc+2
      #pragma unroll
      for (int jj = 0; jj < 2; ++jj) {
        int jA = (wave * 2 + jj) * 2 + (quad >> 1);
        #pragma unroll
        for (int hh = 0; hh < 2; ++hh) {
          int c0 = (cc + 2) * 32 + hh * 16;
          aw[cc & 1][jj][hh] = *(const short8*)(wlin_bf + (jA * 256 + c0 + l16) * 16 + (quad & 1) * 8);
        }
      }
    }
    if (cc < 7) gen_chunk(cc + 1, (cc + 1) & 1, (cc + 1) & 1);

    const short* src = wdbuf + (cc & 1) * 8192;
    short8 A2[2], Bf[4];
    #pragma unroll
    for (int et = 0; et < 2; ++et) {
      int e = wave * 32 + et * 16 + l16;
      int sw = quad ^ ((e >> 1) & 3) ^ ((e >> 5) & 3);
      A2[et] = *(const short8*)&src[e * 32 + sw * 8];
    }
    int chunkY = cc * 4 + quad;
    #pragma unroll
    for (int nt = 0; nt < 4; ++nt) {
      int physc = chunkY ^ l16;                 // nn&15 == l16
      Bf[nt] = *(const short8*)&Ylds[(nt * 16 + l16) * 256 + physc * 8];
    }
    #pragma unroll
    for (int et = 0; et < 2; ++et)
      #pragma unroll
      for (int nt = 0; nt < 4; ++nt)
        acc[et][nt] = __builtin_amdgcn_mfma_f32_16x16x32_bf16(A2[et], Bf[nt], acc[et][nt], 0, 0, 0);
    if (cc < 7) __syncthreads();
  }

  // ---- epilogue: D row=quad*4+r -> e, col=l16 -> pix ----
  float* ob = out + b * 4194304 + (f * 8) * 128 + g * 8;
  #pragma unroll
  for (int et = 0; et < 2; ++et) {
    int e0 = wave * 32 + et * 16 + quad * 4;
    #pragma unroll
    for (int nt = 0; nt < 4; ++nt) {
      int pix = nt * 16 + l16;
      float* oa = ob + (pix >> 3) * 128 + (pix & 7);
      #pragma unroll
      for (int r = 0; r < 4; ++r)
        oa[(e0 + r) * 16384] = acc[et][nt][r];
    }
  }
}

// ============================  launcher  ============================
extern "C" void kernel_launch(void* const* d_in, const int* in_sizes, int n_in,
                              void* d_out, int out_size, void* d_ws, size_t ws_size,
                              hipStream_t stream) {
  const float* x        = (const float*)d_in[0];
  const float* y        = (const float*)d_in[1];
  const float* w_cr     = (const float*)d_in[2];
  const float* b_cr     = (const float*)d_in[3];
  const float* w_dw3    = (const float*)d_in[4];
  const float* b_dw3    = (const float*)d_in[5];
  const float* w_dw7    = (const float*)d_in[6];
  const float* b_dw7    = (const float*)d_in[7];
  const float* w_gate   = (const float*)d_in[8];
  const float* b_gate   = (const float*)d_in[9];
  const float* bn_gamma = (const float*)d_in[10];
  const float* bn_beta  = (const float*)d_in[11];
  const float* bn_mean  = (const float*)d_in[12];
  const float* bn_var   = (const float*)d_in[13];
  const float* sr_scale = (const float*)d_in[14];
  const float* sr_bias  = (const float*)d_in[15];
  const float* w_lin    = (const float*)d_in[16];
  const float* b_lin    = (const float*)d_in[17];
  float* out = (float*)d_out;

  // ws layout: f0 256KB | gs 256KB | wlin_bf 256KB
  float* f0      = (float*)d_ws;
  float* gs      = (float*)((char*)d_ws + 262144);
  short* wlin_bf = (short*)((char*)d_ws + 524288);

  hipLaunchKernelGGL(k1_merged, dim3(640), dim3(256), 0, stream,
                     x, w_cr, b_cr, w_dw3, b_dw3, w_dw7, b_dw7, w_gate, b_gate,
                     bn_gamma, bn_beta, bn_mean, bn_var, sr_scale, sr_bias,
                     w_lin, wlin_bf, f0, gs);
  hipLaunchKernelGGL(k2_fused, dim3(512), dim3(512), 0, stream,
                     y, wlin_bf, f0, gs, b_lin, out);
}